// Round 11
// baseline (171.161 us; speedup 1.0000x reference)
//
#include <hip/hip_runtime.h>
#include <hip/hip_bf16.h>

typedef unsigned short u16;
typedef unsigned int u32;
typedef __attribute__((ext_vector_type(8))) _Float16 f16x8;
typedef __attribute__((ext_vector_type(2))) _Float16 f16x2;
typedef __attribute__((ext_vector_type(4))) float floatx4;

__device__ __forceinline__ u16 f2h(float f){
    union{_Float16 h; u16 u;}v; v.h = (_Float16)f; return v.u;   // RTN
}
__device__ __forceinline__ u32 pkh(float a, float b){
    return (u32)f2h(a) | ((u32)f2h(b) << 16);
}

#define DD 512
#define NTOK 128

// ---------------------------------------------------------------------------
// prep_k: grid (16,8,3), 512 thr. R10-proven, byte-identical (f16 datapath,
// rank-2 position fold: Hf1b = h1+b1+u[n], Hf2 = h2-u[m]).
// ---------------------------------------------------------------------------
__global__ __launch_bounds__(512) void prep_k(
    const float* __restrict__ features, const float* __restrict__ W1,
    const float* __restrict__ W2, const float* __restrict__ b1,
    const float* __restrict__ positions,
    u16* __restrict__ Hf1b, u16* __restrict__ Hf2, u16* __restrict__ W2T)
{
    const int z = blockIdx.z;
    const int tid = threadIdx.x;

    if (z == 2) {   // W2 transpose -> f16
        __shared__ u16 tile[32][33];
        const int tx = tid & 31, ty = tid >> 5;      // ty 0..15
        const int r0 = blockIdx.x * 32, c0 = blockIdx.y * 32;
#pragma unroll
        for (int i = 0; i < 2; ++i) {
            int r = ty + i * 16;
            tile[r][tx] = f2h(W2[(size_t)(r0 + r) * 256 + (c0 + tx)]);
        }
        __syncthreads();
#pragma unroll
        for (int i = 0; i < 2; ++i) {
            int c = ty + i * 16;
            W2T[(size_t)(c0 + c) * 512 + (r0 + tx)] = tile[tx][c];
        }
        return;
    }

    const int bM = blockIdx.x, bN = blockIdx.y;
    u16* outp = z ? Hf2 : Hf1b;
    __shared__ __align__(16) u16 At[64 * 64];
    __shared__ __align__(16) u16 Btl[64 * 64];
    const int wid = tid >> 6, lane = tid & 63, lrow = lane & 15, quad = lane >> 4;
    const int wm = wid >> 1, wn = wid & 1;

    floatx4 acc[2];
    acc[0] = (floatx4)(0.0f); acc[1] = (floatx4)(0.0f);

    const int m = tid >> 3, seg = tid & 7, sw = m & 7;      // A staging map
    const int kr = tid >> 3, csB = tid & 7;                 // B staging map

    for (int kc = 0; kc < 8; ++kc) {
        const int k0 = kc * 64;
        {   // stage A: 8 fp32 -> 8 f16, one uint4, XOR-swizzled
            const float4* src = (const float4*)(features + (size_t)(bM * 64 + m) * DD + k0 + seg * 8);
            float4 f0 = src[0], f1 = src[1];
            *(uint4*)(At + m * 64 + ((seg ^ sw) << 3)) =
                make_uint4(pkh(f0.x, f0.y), pkh(f0.z, f0.w), pkh(f1.x, f1.y), pkh(f1.z, f1.w));
        }
        {   // stage B from W1 rows (transpose-in-write, swizzled scalar b16)
            const float4* src = (const float4*)(W1 + (size_t)(z * 512 + k0 + kr) * DD + bN * 64 + csB * 8);
            float4 g0 = src[0], g1 = src[1];
            float f[8] = { g0.x, g0.y, g0.z, g0.w, g1.x, g1.y, g1.z, g1.w };
            const int chunkB = (kr >> 3), offB = kr & 7;
#pragma unroll
            for (int i = 0; i < 8; ++i) {
                int c = csB * 8 + i;                        // c & 7 == i
                Btl[c * 64 + ((chunkB ^ i) << 3) + offB] = f2h(f[i]);
            }
        }
        __syncthreads();
#pragma unroll
        for (int ks = 0; ks < 2; ++ks) {
            const int ch = ks * 4 + quad;
            int r = wm * 16 + lrow;
            f16x8 afr = *(const f16x8*)(At + r * 64 + ((ch ^ (r & 7)) << 3));
#pragma unroll
            for (int j = 0; j < 2; ++j) {
                int c = wn * 32 + j * 16 + lrow;
                f16x8 bfr = *(const f16x8*)(Btl + c * 64 + ((ch ^ (c & 7)) << 3));
                acc[j] = __builtin_amdgcn_mfma_f32_16x16x32_f16(afr, bfr, acc[j], 0, 0, 0);
            }
        }
        __syncthreads();
    }
#pragma unroll
    for (int j = 0; j < 2; ++j) {
        int col = bN * 64 + wn * 32 + j * 16 + lrow;
        float bb  = z ? 0.0f : b1[col];
        float c0v = W1[(size_t)1024 * DD + col];     // W1c row 0
        float c1v = W1[(size_t)1025 * DD + col];     // W1c row 1
        float sgn = z ? -1.0f : 1.0f;
#pragma unroll
        for (int r = 0; r < 4; ++r) {
            int row = bM * 64 + wm * 16 + quad * 4 + r;     // token index
            float pxr = positions[(size_t)row * 2 + 0];
            float pyr = positions[(size_t)row * 2 + 1];
            outp[(size_t)row * DD + col] =
                f2h(acc[j][r] + bb + sgn * (pxr * c0v + pyr * c1v));
        }
    }
}

// ---------------------------------------------------------------------------
// Fused main — Atile ELIMINATED. Each thread computes its own A-fragments in
// registers: rA[i][ks] = relu(hf2'[row_i, kslice] + s1'[kslice]) — 8 global
// dwordx4 (4 lanes/quad share a 64B line; redundant waves hit L1) + 2
// broadcast s1 LDS reads + 64 packed-f16 ops. Removes ~45% of LDS port
// traffic (A writes + A reads). Freed 16K -> Btile double-buffered in 66.5K
// static LDS, 2 blocks/CU KEPT (the R9 lesson), and the loop needs only ONE
// __syncthreads per kc: its vmcnt(0) drains DMA(kc+1) (in flight since
// before MFMA(kc) — fully covered) + this kc's rA loads (~250cy, covered by
// the co-resident block). DMA(kc+1) issued AFTER sync(kc) -> ordered after
// all waves' MFMA(kc-1) reads of that buffer. Math order identical to R10.
// Register audit: MFMA-phase live = rA 32 + bfr 16 + addr ~10 <= 64 VGPR
// (+64 acc AGPR) — the proven 2-block residency budget.
// ---------------------------------------------------------------------------
__global__ __launch_bounds__(512) void fused_main(
    const u16* __restrict__ Hf1b, const u16* __restrict__ Hf2,
    const u16* __restrict__ W2T, const float* __restrict__ b2,
    const float* __restrict__ W3, const float* __restrict__ b3,
    float* __restrict__ out)
{
    const int b = blockIdx.x, n = blockIdx.y;     // b fastest -> XCD = b
    const int tid = threadIdx.x;
    const int base_bn = b * NTOK + n;
    const int wid = tid >> 6, lane = tid & 63, lrow = lane & 15, quad = lane >> 4;

    __shared__ __align__(16) u16 s1h[DD];        // f16 s1' row, 1 KB
    __shared__ __align__(16) char mbuf[65536];   // Btile[2][256][64] | gh + w3t
    u16* Btile = (u16*)mbuf;                     // 2 x 32K, swizzled, f16
    u16* gh    = (u16*)mbuf;                     // [128][136] epilogue overlay
    u16* w3t   = (u16*)(mbuf + 34816);           // W3^T padded [16][264], epilogue

    // B-DMA lane source pointer: q-invariant swizzle (R0-proven)
    const int csrc = lane >> 3, wsrc = lane & 7;
    const u16* bsrc_lane = W2T + csrc * DD + ((wsrc ^ csrc) << 3);

    auto BDMA = [&](int kc) {   // 4 global_load_lds into buffer kc&1
        const int qoff = (kc & 1) * 16384;
#pragma unroll
        for (int q = 0; q < 4; ++q) {
            const int slot = wid * 4 + q;        // wave-uniform
            __builtin_amdgcn_global_load_lds(
                (const __attribute__((address_space(1))) u32*)(bsrc_lane + slot * 8 * DD + kc * 64),
                (__attribute__((address_space(3))) u32*)(Btile + qoff + slot * 512), 16, 0, 0);
        }
    };

    // issue DMA(0) immediately (nobody reads Bt0 yet; max flight time)
    BDMA(0);

    // ---- phase 0 ----
    {
        int k = tid;  // 512 threads == DD
        s1h[k] = Hf1b[(size_t)base_bn * DD + k];   // b1 + u[n] already folded
    }
    __syncthreads();   // s1h ready (also drains DMA(0), harmless)

    const int wm = wid >> 2, wn = wid & 3;       // main GEMM 2x4 wave grid
    floatx4 acc[4][4];
#pragma unroll
    for (int i = 0; i < 4; ++i)
#pragma unroll
        for (int j = 0; j < 4; ++j) acc[i][j] = (floatx4)(0.0f);

    // per-thread A base: row0 = wm*64 + lrow, k-offset quad*8
    const u16* hfbase = Hf2 + ((size_t)(b * NTOK) + wm * 64 + lrow) * DD + quad * 8;

    const f16x2 zh = {(_Float16)0.0f, (_Float16)0.0f};
    auto hp2 = [&](u32 h, u32 s) -> u32 {
        union { u32 u; f16x2 v; } H, S, O;
        H.u = h; S.u = s;
        O.v = __builtin_elementwise_max(H.v + S.v, zh);
        return O.u;
    };

    // ---- K loop: 1 barrier per kc; A entirely in registers ----
    for (int kc = 0; kc < 8; ++kc) {
        // rA[i][ks] = relu(hf2' + s1') fragments (registers only)
        uint4 rA[4][2];
#pragma unroll
        for (int i = 0; i < 4; ++i)
#pragma unroll
            for (int ks = 0; ks < 2; ++ks)
                rA[i][ks] = *(const uint4*)(hfbase + (size_t)i * 16 * DD + kc * 64 + ks * 32);
        uint4 sfr[2];
#pragma unroll
        for (int ks = 0; ks < 2; ++ks)
            sfr[ks] = *(const uint4*)(s1h + kc * 64 + ks * 32 + quad * 8);
#pragma unroll
        for (int i = 0; i < 4; ++i)
#pragma unroll
            for (int ks = 0; ks < 2; ++ks) {
                rA[i][ks].x = hp2(rA[i][ks].x, sfr[ks].x);
                rA[i][ks].y = hp2(rA[i][ks].y, sfr[ks].y);
                rA[i][ks].z = hp2(rA[i][ks].z, sfr[ks].z);
                rA[i][ks].w = hp2(rA[i][ks].w, sfr[ks].w);
            }

        __syncthreads();   // vmcnt(0)+lgkm(0): B(kc) visible; rA drained

        if (kc < 7) BDMA(kc + 1);   // flies under MFMA(kc), drained next sync

        const int qs = (kc & 1) * 16384;
#pragma unroll
        for (int ks = 0; ks < 2; ++ks) {
            const int ch = ks * 4 + quad;
            f16x8 bfr[4];
#pragma unroll
            for (int j = 0; j < 4; ++j) {
                int c = wn * 64 + j * 16 + lrow;
                bfr[j] = *(const f16x8*)(Btile + qs + c * 64 + ((ch ^ (c & 7)) << 3));
            }
#pragma unroll
            for (int i = 0; i < 4; ++i) {
                union { uint4 u; f16x8 v; } afr;
                afr.u = rA[i][ks];
#pragma unroll
                for (int j = 0; j < 4; ++j)
                    acc[i][j] = __builtin_amdgcn_mfma_f32_16x16x32_f16(afr.v, bfr[j], acc[i][j], 0, 0, 0);
            }
        }
    }
    __syncthreads();   // all MFMA(7) reads of Bt1 done before gh/w3t overlay

    // ---- w3t fill (Btile regions dead now) ----
    {   // w3t: W3 (256x4 fp32) transposed, padded to 16 cols, f16
        int c = tid & 15, kb2 = tid >> 4;          // kb2 0..31
        int k0w = kb2 * 8;
        u32 wv[4];
#pragma unroll
        for (int p = 0; p < 4; ++p) {
            int ka = k0w + p * 2;
            u16 va = (c < 4) ? f2h(W3[ka * 4 + c])       : (u16)0;
            u16 vb = (c < 4) ? f2h(W3[(ka + 1) * 4 + c]) : (u16)0;
            wv[p] = (u32)va | ((u32)vb << 16);
        }
        *(uint2*)(w3t + c * 264 + k0w)     = make_uint2(wv[0], wv[1]);
        *(uint2*)(w3t + c * 264 + k0w + 4) = make_uint2(wv[2], wv[3]);
    }

    // ---- epilogue: relu(acc+b2) -> gh f16 halves -> layer-3 MFMA (R10) ----
    float b2v[4];
#pragma unroll
    for (int j = 0; j < 4; ++j) b2v[j] = b2[wn * 64 + j * 16 + lrow];

    const int smrow = wid * 16;                  // per-wave epilogue row block
    floatx4 acc3 = (floatx4)(0.0f);
#pragma unroll
    for (int half = 0; half < 2; ++half) {
        __syncthreads();
        if ((wn >> 1) == half) {
#pragma unroll
            for (int i = 0; i < 4; ++i)
#pragma unroll
                for (int j = 0; j < 4; ++j)
#pragma unroll
                    for (int r = 0; r < 4; ++r) {
                        int row = wm * 64 + i * 16 + quad * 4 + r;
                        int col = (wn & 1) * 64 + j * 16 + lrow;
                        gh[row * 136 + col] = f2h(fmaxf(acc[i][j][r] + b2v[j], 0.0f));
                    }
        }
        __syncthreads();
#pragma unroll
        for (int ks = 0; ks < 4; ++ks) {
            f16x8 gfrag = *(const f16x8*)(gh + (smrow + lrow) * 136 + ks * 32 + quad * 8);
            f16x8 wfrag = *(const f16x8*)(w3t + lrow * 264 + half * 128 + ks * 32 + quad * 8);
            acc3 = __builtin_amdgcn_mfma_f32_16x16x32_f16(gfrag, wfrag, acc3, 0, 0, 0);
        }
    }
    if (lrow < 4) {
        float bo = b3[lrow];
#pragma unroll
        for (int r = 0; r < 4; ++r) {
            int row = smrow + quad * 4 + r;
            out[(size_t)base_bn * 512 + row * 4 + lrow] = acc3[r] + bo;
        }
    }
}

// ---------------------------------------------------------------------------
extern "C" void kernel_launch(void* const* d_in, const int* in_sizes, int n_in,
                              void* d_out, int out_size, void* d_ws, size_t ws_size,
                              hipStream_t stream)
{
    const float* features  = (const float*)d_in[0];
    const float* positions = (const float*)d_in[1];
    const float* W1 = (const float*)d_in[2];
    const float* b1 = (const float*)d_in[3];
    const float* W2 = (const float*)d_in[4];
    const float* b2 = (const float*)d_in[5];
    const float* W3 = (const float*)d_in[6];
    const float* b3 = (const float*)d_in[7];
    float* out = (float*)d_out;

    char* ws = (char*)d_ws;
    u16* W2T  = (u16*)(ws);                 // 256*512*2 = 262144 B
    u16* Hf1b = (u16*)(ws + 262144);        // 1048576 B
    u16* Hf2  = (u16*)(ws + 1310720);       // 1048576 B (total 2.25 MB)

    prep_k<<<dim3(16, 8, 3), 512, 0, stream>>>(features, W1, W2, b1, positions,
                                               Hf1b, Hf2, W2T);
    fused_main<<<dim3(8, 128), 512, 0, stream>>>(Hf1b, Hf2, W2T, b2, W3, b3, out);
}

// Round 12
// 153.736 us; speedup vs baseline: 1.1133x; 1.1133x over previous
//
#include <hip/hip_runtime.h>
#include <hip/hip_bf16.h>

typedef unsigned short u16;
typedef unsigned int u32;
typedef __attribute__((ext_vector_type(8))) _Float16 f16x8;
typedef __attribute__((ext_vector_type(2))) _Float16 f16x2;
typedef __attribute__((ext_vector_type(4))) float floatx4;

__device__ __forceinline__ u16 f2h(float f){
    union{_Float16 h; u16 u;}v; v.h = (_Float16)f; return v.u;   // RTN
}
__device__ __forceinline__ u32 pkh(float a, float b){
    return (u32)f2h(a) | ((u32)f2h(b) << 16);
}

#define DD 512
#define NTOK 128

// ---------------------------------------------------------------------------
// prep_k: grid (16,8,3), 512 thr. R10-proven, byte-identical (f16 datapath,
// rank-2 position fold: Hf1b = h1+b1+u[n], Hf2 = h2-u[m]).
// ---------------------------------------------------------------------------
__global__ __launch_bounds__(512) void prep_k(
    const float* __restrict__ features, const float* __restrict__ W1,
    const float* __restrict__ W2, const float* __restrict__ b1,
    const float* __restrict__ positions,
    u16* __restrict__ Hf1b, u16* __restrict__ Hf2, u16* __restrict__ W2T)
{
    const int z = blockIdx.z;
    const int tid = threadIdx.x;

    if (z == 2) {   // W2 transpose -> f16
        __shared__ u16 tile[32][33];
        const int tx = tid & 31, ty = tid >> 5;      // ty 0..15
        const int r0 = blockIdx.x * 32, c0 = blockIdx.y * 32;
#pragma unroll
        for (int i = 0; i < 2; ++i) {
            int r = ty + i * 16;
            tile[r][tx] = f2h(W2[(size_t)(r0 + r) * 256 + (c0 + tx)]);
        }
        __syncthreads();
#pragma unroll
        for (int i = 0; i < 2; ++i) {
            int c = ty + i * 16;
            W2T[(size_t)(c0 + c) * 512 + (r0 + tx)] = tile[tx][c];
        }
        return;
    }

    const int bM = blockIdx.x, bN = blockIdx.y;
    u16* outp = z ? Hf2 : Hf1b;
    __shared__ __align__(16) u16 At[64 * 64];
    __shared__ __align__(16) u16 Btl[64 * 64];
    const int wid = tid >> 6, lane = tid & 63, lrow = lane & 15, quad = lane >> 4;
    const int wm = wid >> 1, wn = wid & 1;

    floatx4 acc[2];
    acc[0] = (floatx4)(0.0f); acc[1] = (floatx4)(0.0f);

    const int m = tid >> 3, seg = tid & 7, sw = m & 7;      // A staging map
    const int kr = tid >> 3, csB = tid & 7;                 // B staging map

    for (int kc = 0; kc < 8; ++kc) {
        const int k0 = kc * 64;
        {   // stage A: 8 fp32 -> 8 f16, one uint4, XOR-swizzled
            const float4* src = (const float4*)(features + (size_t)(bM * 64 + m) * DD + k0 + seg * 8);
            float4 f0 = src[0], f1 = src[1];
            *(uint4*)(At + m * 64 + ((seg ^ sw) << 3)) =
                make_uint4(pkh(f0.x, f0.y), pkh(f0.z, f0.w), pkh(f1.x, f1.y), pkh(f1.z, f1.w));
        }
        {   // stage B from W1 rows (transpose-in-write, swizzled scalar b16)
            const float4* src = (const float4*)(W1 + (size_t)(z * 512 + k0 + kr) * DD + bN * 64 + csB * 8);
            float4 g0 = src[0], g1 = src[1];
            float f[8] = { g0.x, g0.y, g0.z, g0.w, g1.x, g1.y, g1.z, g1.w };
            const int chunkB = (kr >> 3), offB = kr & 7;
#pragma unroll
            for (int i = 0; i < 8; ++i) {
                int c = csB * 8 + i;                        // c & 7 == i
                Btl[c * 64 + ((chunkB ^ i) << 3) + offB] = f2h(f[i]);
            }
        }
        __syncthreads();
#pragma unroll
        for (int ks = 0; ks < 2; ++ks) {
            const int ch = ks * 4 + quad;
            int r = wm * 16 + lrow;
            f16x8 afr = *(const f16x8*)(At + r * 64 + ((ch ^ (r & 7)) << 3));
#pragma unroll
            for (int j = 0; j < 2; ++j) {
                int c = wn * 32 + j * 16 + lrow;
                f16x8 bfr = *(const f16x8*)(Btl + c * 64 + ((ch ^ (c & 7)) << 3));
                acc[j] = __builtin_amdgcn_mfma_f32_16x16x32_f16(afr, bfr, acc[j], 0, 0, 0);
            }
        }
        __syncthreads();
    }
#pragma unroll
    for (int j = 0; j < 2; ++j) {
        int col = bN * 64 + wn * 32 + j * 16 + lrow;
        float bb  = z ? 0.0f : b1[col];
        float c0v = W1[(size_t)1024 * DD + col];     // W1c row 0
        float c1v = W1[(size_t)1025 * DD + col];     // W1c row 1
        float sgn = z ? -1.0f : 1.0f;
#pragma unroll
        for (int r = 0; r < 4; ++r) {
            int row = bM * 64 + wm * 16 + quad * 4 + r;     // token index
            float pxr = positions[(size_t)row * 2 + 0];
            float pyr = positions[(size_t)row * 2 + 1];
            outp[(size_t)row * DD + col] =
                f2h(acc[j][r] + bb + sgn * (pxr * c0v + pyr * c1v));
        }
    }
}

// ---------------------------------------------------------------------------
// Fused main — R10 frame (LDS Atile staging, DMA B-transport, swizzles,
// 2 syncs/kc, math order) re-partitioned onto 4 waves (256 thr), wave grid
// 2m x 2n, acc[4][8] = 128 AGPR/wave. Rationale: kernel is LDS-port-bound
// (port ~95% busy, fragment reads 2/3 of traffic); doubling per-wave acc
// raises FLOP/fragment-read 33% and cuts total fragment reads 128->96 b128
// per block-kc. Registers 128 AGPR + ~64 VGPR = 192/wave (occupancy-safe);
// LDS 50.2K -> 3 blocks/CU. R11's mistake (redundant global A loads) NOT
// repeated — A still staged once through LDS. absmax identical (same
// per-element accumulation order).
// ---------------------------------------------------------------------------
__global__ __launch_bounds__(256) void fused_main(
    const u16* __restrict__ Hf1b, const u16* __restrict__ Hf2,
    const u16* __restrict__ W2T, const float* __restrict__ b2,
    const float* __restrict__ W3, const float* __restrict__ b3,
    float* __restrict__ out)
{
    const int b = blockIdx.x, n = blockIdx.y;     // b fastest -> XCD = b
    const int tid = threadIdx.x;
    const int base_bn = b * NTOK + n;
    const int wid = tid >> 6, lane = tid & 63, lrow = lane & 15, quad = lane >> 4;

    __shared__ __align__(16) u16 s1h[DD];        // f16 s1' row, 1 KB
    __shared__ __align__(16) char mbuf[49152];   // Atile 16K + Btile 32K | gh 34K + w3t 8.25K
    u16* Atile = (u16*)mbuf;                     // [128][64] swizzled, f16
    u16* Btile = (u16*)(mbuf + 16384);           // [256][64] swizzled, f16
    u16* gh    = (u16*)mbuf;                     // [128][136] epilogue overlay
    u16* w3t   = (u16*)(mbuf + 34816);           // W3^T padded [16][264], epilogue

    // ---- phase 0 ----
    {
        s1h[tid]       = Hf1b[(size_t)base_bn * DD + tid];
        s1h[tid + 256] = Hf1b[(size_t)base_bn * DD + tid + 256];
    }
    const int mrow = tid >> 1, seg2 = tid & 1, swA = mrow & 7;
    // B-DMA lane source pointer: q-invariant swizzle (R0-proven)
    const int csrc = lane >> 3, wsrc = lane & 7;
    const u16* bsrc_lane = W2T + csrc * DD + ((wsrc ^ csrc) << 3);
    __syncthreads();

    const int wm = wid >> 1, wn = wid & 1;       // 2x2 wave grid
    floatx4 acc[4][8];
#pragma unroll
    for (int i = 0; i < 4; ++i)
#pragma unroll
        for (int j = 0; j < 8; ++j) acc[i][j] = (floatx4)(0.0f);

    const u16* hf2p = Hf2 + (size_t)(b * NTOK + mrow) * DD;

    const f16x2 zh = {(_Float16)0.0f, (_Float16)0.0f};
    auto hp2 = [&](u32 h, u32 s) -> u32 {
        union { u32 u; f16x2 v; } H, S, O;
        H.u = h; S.u = s;
        O.v = __builtin_elementwise_max(H.v + S.v, zh);
        return O.u;
    };

    // ---- K loop (R10 structure; 4 waves) ----
    for (int kc = 0; kc < 8; ++kc) {
        const int k0 = kc * 64;
        // stage B via LDS-DMA first: 8 slots per wave (32 total, R10 layout)
#pragma unroll
        for (int q = 0; q < 8; ++q) {
            const int slot = wid * 8 + q;        // wave-uniform
            __builtin_amdgcn_global_load_lds(
                (const __attribute__((address_space(1))) u32*)(bsrc_lane + slot * 8 * DD + k0),
                (__attribute__((address_space(3))) u32*)(Btile + slot * 512), 16, 0, 0);
        }

        const int kb = k0 + seg2 * 32;
        {   // stage A: h = relu(hf2' + s1'), 32 f16/thread (4 uint4)
#pragma unroll
            for (int t = 0; t < 4; ++t) {
                uint4 hv = *(const uint4*)(hf2p + kb + t * 8);
                uint4 sv = *(const uint4*)(s1h + kb + t * 8);
                uint4 o = make_uint4(hp2(hv.x, sv.x), hp2(hv.y, sv.y),
                                     hp2(hv.z, sv.z), hp2(hv.w, sv.w));
                *(uint4*)(Atile + mrow * 64 + (((seg2 * 4 + t) ^ swA) << 3)) = o;
            }
        }
        __syncthreads();   // vmcnt(0)+lgkmcnt(0) drain: Atile and B-DMA ready
#pragma unroll
        for (int ks = 0; ks < 2; ++ks) {
            const int ch = ks * 4 + quad;
            f16x8 afr[4], bfr[8];
#pragma unroll
            for (int i = 0; i < 4; ++i) {
                int r = wm * 64 + i * 16 + lrow;
                afr[i] = *(const f16x8*)(Atile + r * 64 + ((ch ^ (r & 7)) << 3));
            }
#pragma unroll
            for (int j = 0; j < 8; ++j) {
                int c = wn * 128 + j * 16 + lrow;
                bfr[j] = *(const f16x8*)(Btile + c * 64 + ((ch ^ (c & 7)) << 3));
            }
#pragma unroll
            for (int i = 0; i < 4; ++i)
#pragma unroll
                for (int j = 0; j < 8; ++j)
                    acc[i][j] = __builtin_amdgcn_mfma_f32_16x16x32_f16(afr[i], bfr[j], acc[i][j], 0, 0, 0);
        }
        __syncthreads();
    }

    // ---- w3t fill (Btile region dead after K loop's final sync) ----
#pragma unroll
    for (int it = 0; it < 2; ++it) {
        int c = tid & 15, kb2 = (tid >> 4) + it * 16;   // kb2 0..31
        int k0w = kb2 * 8;
        u32 wv[4];
#pragma unroll
        for (int p = 0; p < 4; ++p) {
            int ka = k0w + p * 2;
            u16 va = (c < 4) ? f2h(W3[ka * 4 + c])       : (u16)0;
            u16 vb = (c < 4) ? f2h(W3[(ka + 1) * 4 + c]) : (u16)0;
            wv[p] = (u32)va | ((u32)vb << 16);
        }
        *(uint2*)(w3t + c * 264 + k0w)     = make_uint2(wv[0], wv[1]);
        *(uint2*)(w3t + c * 264 + k0w + 4) = make_uint2(wv[2], wv[3]);
    }

    // ---- epilogue: relu(acc+b2) -> gh f16 halves -> layer-3 MFMA ----
    float b2v[8];
#pragma unroll
    for (int j = 0; j < 8; ++j) b2v[j] = b2[wn * 128 + j * 16 + lrow];

    floatx4 acc3[2];
    acc3[0] = (floatx4)(0.0f); acc3[1] = (floatx4)(0.0f);
#pragma unroll
    for (int half = 0; half < 2; ++half) {
        __syncthreads();
        if (wn == half) {
#pragma unroll
            for (int i = 0; i < 4; ++i)
#pragma unroll
                for (int j = 0; j < 8; ++j)
#pragma unroll
                    for (int r = 0; r < 4; ++r) {
                        int row = wm * 64 + i * 16 + quad * 4 + r;
                        int col = j * 16 + lrow;
                        gh[row * 136 + col] = f2h(fmaxf(acc[i][j][r] + b2v[j], 0.0f));
                    }
        }
        __syncthreads();
#pragma unroll
        for (int g = 0; g < 2; ++g) {
            const int grow = wid * 32 + g * 16;
#pragma unroll
            for (int ks = 0; ks < 4; ++ks) {
                f16x8 gfrag = *(const f16x8*)(gh + (grow + lrow) * 136 + ks * 32 + quad * 8);
                f16x8 wfrag = *(const f16x8*)(w3t + lrow * 264 + half * 128 + ks * 32 + quad * 8);
                acc3[g] = __builtin_amdgcn_mfma_f32_16x16x32_f16(gfrag, wfrag, acc3[g], 0, 0, 0);
            }
        }
    }
    if (lrow < 4) {
        float bo = b3[lrow];
#pragma unroll
        for (int g = 0; g < 2; ++g)
#pragma unroll
            for (int r = 0; r < 4; ++r) {
                int row = wid * 32 + g * 16 + quad * 4 + r;
                out[(size_t)base_bn * 512 + row * 4 + lrow] = acc3[g][r] + bo;
            }
    }
}

// ---------------------------------------------------------------------------
extern "C" void kernel_launch(void* const* d_in, const int* in_sizes, int n_in,
                              void* d_out, int out_size, void* d_ws, size_t ws_size,
                              hipStream_t stream)
{
    const float* features  = (const float*)d_in[0];
    const float* positions = (const float*)d_in[1];
    const float* W1 = (const float*)d_in[2];
    const float* b1 = (const float*)d_in[3];
    const float* W2 = (const float*)d_in[4];
    const float* b2 = (const float*)d_in[5];
    const float* W3 = (const float*)d_in[6];
    const float* b3 = (const float*)d_in[7];
    float* out = (float*)d_out;

    char* ws = (char*)d_ws;
    u16* W2T  = (u16*)(ws);                 // 256*512*2 = 262144 B
    u16* Hf1b = (u16*)(ws + 262144);        // 1048576 B
    u16* Hf2  = (u16*)(ws + 1310720);       // 1048576 B (total 2.25 MB)

    prep_k<<<dim3(16, 8, 3), 512, 0, stream>>>(features, W1, W2, b1, positions,
                                               Hf1b, Hf2, W2T);
    fused_main<<<dim3(8, 128), 256, 0, stream>>>(Hf1b, Hf2, W2T, b2, W3, b3, out);
}

// Round 13
// 115.981 us; speedup vs baseline: 1.4758x; 1.3255x over previous
//
#include <hip/hip_runtime.h>
#include <hip/hip_bf16.h>

typedef unsigned short u16;
typedef unsigned int u32;
typedef __attribute__((ext_vector_type(8))) _Float16 f16x8;
typedef __attribute__((ext_vector_type(2))) _Float16 f16x2;
typedef __attribute__((ext_vector_type(4))) float floatx4;

__device__ __forceinline__ u16 f2h(float f){
    union{_Float16 h; u16 u;}v; v.h = (_Float16)f; return v.u;   // RTN
}
__device__ __forceinline__ u32 pkh(float a, float b){
    return (u32)f2h(a) | ((u32)f2h(b) << 16);
}

#define DD 512
#define NTOK 128

// ---------------------------------------------------------------------------
// prep_k: grid (16,8,3), 512 thr. R10-proven (f16 datapath, rank-2 position
// fold: Hf1b = h1+b1+u[n], Hf2 = h2-u[m]).
// ---------------------------------------------------------------------------
__global__ __launch_bounds__(512) void prep_k(
    const float* __restrict__ features, const float* __restrict__ W1,
    const float* __restrict__ W2, const float* __restrict__ b1,
    const float* __restrict__ positions,
    u16* __restrict__ Hf1b, u16* __restrict__ Hf2, u16* __restrict__ W2T)
{
    const int z = blockIdx.z;
    const int tid = threadIdx.x;

    if (z == 2) {   // W2 transpose -> f16
        __shared__ u16 tile[32][33];
        const int tx = tid & 31, ty = tid >> 5;      // ty 0..15
        const int r0 = blockIdx.x * 32, c0 = blockIdx.y * 32;
#pragma unroll
        for (int i = 0; i < 2; ++i) {
            int r = ty + i * 16;
            tile[r][tx] = f2h(W2[(size_t)(r0 + r) * 256 + (c0 + tx)]);
        }
        __syncthreads();
#pragma unroll
        for (int i = 0; i < 2; ++i) {
            int c = ty + i * 16;
            W2T[(size_t)(c0 + c) * 512 + (r0 + tx)] = tile[tx][c];
        }
        return;
    }

    const int bM = blockIdx.x, bN = blockIdx.y;
    u16* outp = z ? Hf2 : Hf1b;
    __shared__ __align__(16) u16 At[64 * 64];
    __shared__ __align__(16) u16 Btl[64 * 64];
    const int wid = tid >> 6, lane = tid & 63, lrow = lane & 15, quad = lane >> 4;
    const int wm = wid >> 1, wn = wid & 1;

    floatx4 acc[2];
    acc[0] = (floatx4)(0.0f); acc[1] = (floatx4)(0.0f);

    const int m = tid >> 3, seg = tid & 7, sw = m & 7;      // A staging map
    const int kr = tid >> 3, csB = tid & 7;                 // B staging map

    for (int kc = 0; kc < 8; ++kc) {
        const int k0 = kc * 64;
        {   // stage A: 8 fp32 -> 8 f16, one uint4, XOR-swizzled
            const float4* src = (const float4*)(features + (size_t)(bM * 64 + m) * DD + k0 + seg * 8);
            float4 f0 = src[0], f1 = src[1];
            *(uint4*)(At + m * 64 + ((seg ^ sw) << 3)) =
                make_uint4(pkh(f0.x, f0.y), pkh(f0.z, f0.w), pkh(f1.x, f1.y), pkh(f1.z, f1.w));
        }
        {   // stage B from W1 rows (transpose-in-write, swizzled scalar b16)
            const float4* src = (const float4*)(W1 + (size_t)(z * 512 + k0 + kr) * DD + bN * 64 + csB * 8);
            float4 g0 = src[0], g1 = src[1];
            float f[8] = { g0.x, g0.y, g0.z, g0.w, g1.x, g1.y, g1.z, g1.w };
            const int chunkB = (kr >> 3), offB = kr & 7;
#pragma unroll
            for (int i = 0; i < 8; ++i) {
                int c = csB * 8 + i;                        // c & 7 == i
                Btl[c * 64 + ((chunkB ^ i) << 3) + offB] = f2h(f[i]);
            }
        }
        __syncthreads();
#pragma unroll
        for (int ks = 0; ks < 2; ++ks) {
            const int ch = ks * 4 + quad;
            int r = wm * 16 + lrow;
            f16x8 afr = *(const f16x8*)(At + r * 64 + ((ch ^ (r & 7)) << 3));
#pragma unroll
            for (int j = 0; j < 2; ++j) {
                int c = wn * 32 + j * 16 + lrow;
                f16x8 bfr = *(const f16x8*)(Btl + c * 64 + ((ch ^ (c & 7)) << 3));
                acc[j] = __builtin_amdgcn_mfma_f32_16x16x32_f16(afr, bfr, acc[j], 0, 0, 0);
            }
        }
        __syncthreads();
    }
#pragma unroll
    for (int j = 0; j < 2; ++j) {
        int col = bN * 64 + wn * 32 + j * 16 + lrow;
        float bb  = z ? 0.0f : b1[col];
        float c0v = W1[(size_t)1024 * DD + col];     // W1c row 0
        float c1v = W1[(size_t)1025 * DD + col];     // W1c row 1
        float sgn = z ? -1.0f : 1.0f;
#pragma unroll
        for (int r = 0; r < 4; ++r) {
            int row = bM * 64 + wm * 16 + quad * 4 + r;     // token index
            float pxr = positions[(size_t)row * 2 + 0];
            float pyr = positions[(size_t)row * 2 + 1];
            outp[(size_t)row * DD + col] =
                f2h(acc[j][r] + bb + sgn * (pxr * c0v + pyr * c1v));
        }
    }
}

// ---------------------------------------------------------------------------
// Fused main — R10 verbatim: the measured constrained optimum of this
// structure. Constraints established by the 13-round sweep:
//  * per-wave acc footprint = 64 regs exactly (R12: 128 -> VGPR 200, 1 blk/CU)
//  * residency 2-3 blocks/CU (R9: 1 -> +16us; R4: 3rd block null)
//  * A staged through LDS once (R11: reg-A -> 2x global traffic)
//  * B via global_load_lds (R6: reg-staged -16%)
//  * 2-barrier lockstep (R5: dbuf+1-barrier -8%)
//  * f16 packed datapath (R8), position term rank-2-folded in prep (R10)
// ---------------------------------------------------------------------------
__global__ __launch_bounds__(512) void fused_main(
    const u16* __restrict__ Hf1b, const u16* __restrict__ Hf2,
    const u16* __restrict__ W2T, const float* __restrict__ b2,
    const float* __restrict__ W3, const float* __restrict__ b3,
    float* __restrict__ out)
{
    const int b = blockIdx.x, n = blockIdx.y;     // b fastest -> XCD = b
    const int tid = threadIdx.x;
    const int base_bn = b * NTOK + n;
    const int wid = tid >> 6, lane = tid & 63, lrow = lane & 15, quad = lane >> 4;

    __shared__ __align__(16) u16 s1h[DD];        // f16 s1' row, 1 KB
    __shared__ __align__(16) char mbuf[49152];   // Atile 16K + Btile 32K | gh 34K + w3t 8.25K
    u16* Atile = (u16*)mbuf;                     // [128][64] swizzled, f16
    u16* Btile = (u16*)(mbuf + 16384);           // [256][64] swizzled, f16
    u16* gh    = (u16*)mbuf;                     // [128][136] epilogue overlay
    u16* w3t   = (u16*)(mbuf + 34816);           // W3^T padded [16][264], epilogue-only

    // ---- phase 0 ----
    {
        int k = tid;  // 512 threads == DD
        s1h[k] = Hf1b[(size_t)base_bn * DD + k];   // b1 + u[n] already folded
    }
    const int mrow = tid >> 2, seg = tid & 3, swA = mrow & 7;
    // B-DMA lane source pointer: q-invariant swizzle (R0-proven)
    const int csrc = lane >> 3, wsrc = lane & 7;
    const u16* bsrc_lane = W2T + csrc * DD + ((wsrc ^ csrc) << 3);
    __syncthreads();

    const int wm = wid >> 2, wn = wid & 3;       // main GEMM 2x4 wave grid
    floatx4 acc[4][4];
#pragma unroll
    for (int i = 0; i < 4; ++i)
#pragma unroll
        for (int j = 0; j < 4; ++j) acc[i][j] = (floatx4)(0.0f);

    const u16* hf2p = Hf2 + (size_t)(b * NTOK + mrow) * DD;

    const f16x2 zh = {(_Float16)0.0f, (_Float16)0.0f};
    auto hp2 = [&](u32 h, u32 s) -> u32 {
        union { u32 u; f16x2 v; } H, S, O;
        H.u = h; S.u = s;
        O.v = __builtin_elementwise_max(H.v + S.v, zh);
        return O.u;
    };

    // ---- K loop (R8 structure; A-stage = packed add+relu only) ----
    for (int kc = 0; kc < 8; ++kc) {
        const int k0 = kc * 64;
        // stage B via LDS-DMA first (zero data regs; latency hidden by stage-A)
#pragma unroll
        for (int q = 0; q < 4; ++q) {
            const int slot = wid * 4 + q;        // wave-uniform
            __builtin_amdgcn_global_load_lds(
                (const __attribute__((address_space(1))) u32*)(bsrc_lane + slot * 8 * DD + k0),
                (__attribute__((address_space(3))) u32*)(Btile + slot * 512), 16, 0, 0);
        }

        const int kb = k0 + seg * 16;
        {   // stage A: h = relu(hf2' + s1'), 16 f16/thread
            uint4 hv  = *(const uint4*)(hf2p + kb);
            uint4 hw  = *(const uint4*)(hf2p + kb + 8);
            uint4 sv  = *(const uint4*)(s1h + kb);
            uint4 sw2 = *(const uint4*)(s1h + kb + 8);
            uint4 o0 = make_uint4(hp2(hv.x, sv.x), hp2(hv.y, sv.y),
                                  hp2(hv.z, sv.z), hp2(hv.w, sv.w));
            uint4 o1 = make_uint4(hp2(hw.x, sw2.x), hp2(hw.y, sw2.y),
                                  hp2(hw.z, sw2.z), hp2(hw.w, sw2.w));
            *(uint4*)(Atile + mrow * 64 + (((seg * 2    ) ^ swA) << 3)) = o0;
            *(uint4*)(Atile + mrow * 64 + (((seg * 2 + 1) ^ swA) << 3)) = o1;
        }
        __syncthreads();   // vmcnt(0)+lgkmcnt(0) drain: Atile and B-DMA ready
#pragma unroll
        for (int ks = 0; ks < 2; ++ks) {
            const int ch = ks * 4 + quad;
            f16x8 afr[4], bfr[4];
#pragma unroll
            for (int i = 0; i < 4; ++i) {
                int r = wm * 64 + i * 16 + lrow;
                afr[i] = *(const f16x8*)(Atile + r * 64 + ((ch ^ (r & 7)) << 3));
            }
#pragma unroll
            for (int j = 0; j < 4; ++j) {
                int c = wn * 64 + j * 16 + lrow;
                bfr[j] = *(const f16x8*)(Btile + c * 64 + ((ch ^ (c & 7)) << 3));
            }
#pragma unroll
            for (int i = 0; i < 4; ++i)
#pragma unroll
                for (int j = 0; j < 4; ++j)
                    acc[i][j] = __builtin_amdgcn_mfma_f32_16x16x32_f16(afr[i], bfr[j], acc[i][j], 0, 0, 0);
        }
        __syncthreads();
    }

    // ---- w3t fill (Btile region dead after K loop) ----
    {   // w3t: W3 (256x4 fp32) transposed, padded to 16 cols, f16
        int c = tid & 15, kb2 = tid >> 4;          // kb2 0..31
        int k0w = kb2 * 8;
        u32 wv[4];
#pragma unroll
        for (int p = 0; p < 4; ++p) {
            int ka = k0w + p * 2;
            u16 va = (c < 4) ? f2h(W3[ka * 4 + c])       : (u16)0;
            u16 vb = (c < 4) ? f2h(W3[(ka + 1) * 4 + c]) : (u16)0;
            wv[p] = (u32)va | ((u32)vb << 16);
        }
        *(uint2*)(w3t + c * 264 + k0w)     = make_uint2(wv[0], wv[1]);
        *(uint2*)(w3t + c * 264 + k0w + 4) = make_uint2(wv[2], wv[3]);
    }

    // ---- epilogue: relu(acc+b2) -> gh f16 halves -> layer-3 MFMA (R8) ----
    float b2v[4];
#pragma unroll
    for (int j = 0; j < 4; ++j) b2v[j] = b2[wn * 64 + j * 16 + lrow];

    const int smrow = wid * 16;                  // per-wave epilogue row block
    floatx4 acc3 = (floatx4)(0.0f);
#pragma unroll
    for (int half = 0; half < 2; ++half) {
        __syncthreads();
        if ((wn >> 1) == half) {
#pragma unroll
            for (int i = 0; i < 4; ++i)
#pragma unroll
                for (int j = 0; j < 4; ++j)
#pragma unroll
                    for (int r = 0; r < 4; ++r) {
                        int row = wm * 64 + i * 16 + quad * 4 + r;
                        int col = (wn & 1) * 64 + j * 16 + lrow;
                        gh[row * 136 + col] = f2h(fmaxf(acc[i][j][r] + b2v[j], 0.0f));
                    }
        }
        __syncthreads();
#pragma unroll
        for (int ks = 0; ks < 4; ++ks) {
            f16x8 gfrag = *(const f16x8*)(gh + (smrow + lrow) * 136 + ks * 32 + quad * 8);
            f16x8 wfrag = *(const f16x8*)(w3t + lrow * 264 + half * 128 + ks * 32 + quad * 8);
            acc3 = __builtin_amdgcn_mfma_f32_16x16x32_f16(gfrag, wfrag, acc3, 0, 0, 0);
        }
    }
    if (lrow < 4) {
        float bo = b3[lrow];
#pragma unroll
        for (int r = 0; r < 4; ++r) {
            int row = smrow + quad * 4 + r;
            out[(size_t)base_bn * 512 + row * 4 + lrow] = acc3[r] + bo;
        }
    }
}

// ---------------------------------------------------------------------------
extern "C" void kernel_launch(void* const* d_in, const int* in_sizes, int n_in,
                              void* d_out, int out_size, void* d_ws, size_t ws_size,
                              hipStream_t stream)
{
    const float* features  = (const float*)d_in[0];
    const float* positions = (const float*)d_in[1];
    const float* W1 = (const float*)d_in[2];
    const float* b1 = (const float*)d_in[3];
    const float* W2 = (const float*)d_in[4];
    const float* b2 = (const float*)d_in[5];
    const float* W3 = (const float*)d_in[6];
    const float* b3 = (const float*)d_in[7];
    float* out = (float*)d_out;

    char* ws = (char*)d_ws;
    u16* W2T  = (u16*)(ws);                 // 256*512*2 = 262144 B
    u16* Hf1b = (u16*)(ws + 262144);        // 1048576 B
    u16* Hf2  = (u16*)(ws + 1310720);       // 1048576 B (total 2.25 MB)

    prep_k<<<dim3(16, 8, 3), 512, 0, stream>>>(features, W1, W2, b1, positions,
                                               Hf1b, Hf2, W2T);
    fused_main<<<dim3(8, 128), 512, 0, stream>>>(Hf1b, Hf2, W2T, b2, W3, b3, out);
}